// Round 10
// baseline (441.654 us; speedup 1.0000x reference)
//
#include <hip/hip_runtime.h>
#include <math.h>

#define NNODES 100000
#define NEDGES 1600000
#define NBATCH 64
#define NTILES (NEDGES/64)   // 25000 tiles of 64 edges (4 nodes)

typedef __attribute__((ext_vector_type(8))) short  short8;
typedef __attribute__((ext_vector_type(4))) short  short4v;
typedef __attribute__((ext_vector_type(2))) unsigned int uint2v;
typedef __attribute__((ext_vector_type(4))) float  float4v;
typedef unsigned short ushort_t;

__device__ __forceinline__ short f2bf(float f) {           // RTNE fp32->bf16
    unsigned u = __builtin_bit_cast(unsigned, f);
    u += 0x7fffu + ((u >> 16) & 1u);
    return (short)(u >> 16);
}
__device__ __forceinline__ float b2f(short s) {
    unsigned u = ((unsigned)(unsigned short)s) << 16;
    return __builtin_bit_cast(float, u);
}
// 2×f32 -> packed 2×bf16 in one VALU op (lo -> low 16 bits).
__device__ __forceinline__ unsigned cvt_pk_bf16(float lo, float hi) {
    unsigned r;
    asm("v_cvt_pk_bf16_f32 %0, %1, %2" : "=v"(r) : "v"(lo), "v"(hi));
    return r;
}
// max over the 4 16-lane groups {c, c+16, c+32, c+48} without DS ops:
// permlane16/32 swaps are VALU (keeps the LDS pipe free).
__device__ __forceinline__ float red_groups_max(float m) {
    unsigned a = __builtin_bit_cast(unsigned, m), b = a;
    asm("v_permlane16_swap_b32 %0, %1" : "+v"(a), "+v"(b));
    m = fmaxf(__builtin_bit_cast(float, a), __builtin_bit_cast(float, b));
    a = __builtin_bit_cast(unsigned, m); b = a;
    asm("v_permlane32_swap_b32 %0, %1" : "+v"(a), "+v"(b));
    return fmaxf(__builtin_bit_cast(float, a), __builtin_bit_cast(float, b));
}

// Barrier that releases LDS writes but leaves global prefetch loads in
// flight (__syncthreads would drain vmcnt(0) -> the m97 barrier-drain stall).
__device__ __forceinline__ void barrier_lds_only() {
    asm volatile("s_waitcnt lgkmcnt(0)" ::: "memory");
    __builtin_amdgcn_sched_barrier(0);
    __builtin_amdgcn_s_barrier();
    __builtin_amdgcn_sched_barrier(0);
}

// bf16 MFMA layer. Per-wave output blocks are 32 WIDE (2 m-tiles GEMM1 /
// 2 channel-frags GEMM2) so every ds_read_b128 feeds TWO MFMAs. Epilogue-2
// cross-lane max uses v_permlane*_swap (VALU, no DS). Round-10: grid sized
// for 4 blocks/CU (VGPR=64 -> 8 waves/SIMD exactly fills the 512-reg file;
// LDS 30.7KB x4 = 123KB < 160KB) -- round 9's 2-block grid capped occupancy
// at 40% while no pipe was saturated.
// GEMM1: A = W^T (M=h), B = x^T (N=edges). GEMM2 flipped: A = y (M=edges),
// B = W (N=channels). D layout (m89): col=lane&15, row=(lane>>4)*4+reg.
template<int CIN, int H, int O, int NWAVES, int MINW>
__global__ __launch_bounds__(NWAVES*64, MINW)
void layer_mfma(const ushort_t* __restrict__ hin, const float* __restrict__ pos,
                const int* __restrict__ srcArr,
                const float* __restrict__ wa, const float* __restrict__ ba,
                const float* __restrict__ wb, const float* __restrict__ bb,
                ushort_t* __restrict__ hout)
{
    constexpr int K1   = CIN + 3;
    constexpr int S1   = ((K1 + 31) / 32) * 32;  // padded K of GEMM1
    constexpr int NS1  = S1 / 32;
    constexpr int NS2  = H / 32;
    // GEMM1 wave split: 32-wide h-block x edge-group
    constexpr int HB1  = H / 32;
    constexpr int EH1  = NWAVES / HB1;
    constexpr int E1   = 64 / EH1;               // edges per group
    constexpr int NT1  = E1 / 16;
    // GEMM2 wave split: 32-wide channel-block x edge-group
    constexpr int CB2  = O / 32;
    constexpr int EH2  = NWAVES / CB2;
    constexpr int E2   = 64 / EH2;
    constexpr int MT2  = E2 / 16;
    constexpr int RSX  = S1 + 8;                 // x row stride (shorts)
    constexpr int RSY  = H + 8;

    __shared__ short smem[64 * RSX + 64 * RSY];
    short* xs = smem;            // [64 edges][x bf16 (S1) | pad]
    short* ys = smem + 64 * RSX; // [64 edges][y bf16 (H)  | pad]

    const int tid  = threadIdx.x;
    const int lane = tid & 63;
    const int w    = tid >> 6;   // wave id
    const int g    = lane >> 4;  // k-group / row-group
    const int c    = lane & 15;
    const int e    = tid & 63;   // edge-in-tile this thread stages
    const int rep  = tid >> 6;   // 8-short slice of the row this thread stages
    const int hb   = w / EH1;    // GEMM1 h-block (32 wide)
    const int eg1  = w % EH1;    // GEMM1 edge group
    const int cb2  = w / EH2;    // GEMM2 channel block (32 wide)
    const int eg2  = w % EH2;    // GEMM2 edge group
    const int STRIDE = gridDim.x;

    // Zero LDS once: K-pad columns must read as 0.
    {
        short4v z4 = (short4v)0;
        for (int i = tid; i < (64*RSX + 64*RSY)/4; i += NWAVES*64)
            ((short4v*)smem)[i] = z4;
    }

    // ---- prefetch state: gather rows/pos for tile `targ`, then advance srcN.
    int srcN = srcArr[blockIdx.x * 64 + e];
    short8 pA;
    float ps0, ps1, ps2, pd0, pd1, pd2;
    auto issue = [&](int targ) {
        const int src = srcN;
        if constexpr (CIN == 3) {
            if (rep == 0) {
                ps0 = pos[src*3+0]; ps1 = pos[src*3+1]; ps2 = pos[src*3+2];
                const int node = targ*4 + (e >> 4);
                pd0 = pos[node*3+0]; pd1 = pos[node*3+1]; pd2 = pos[node*3+2];
            }
        } else {
            pA = *(const short8*)(hin + (size_t)src * CIN + rep*8);
            if (rep == 0) {
                ps0 = pos[src*3+0]; ps1 = pos[src*3+1]; ps2 = pos[src*3+2];
                const int node = targ*4 + (e >> 4);
                pd0 = pos[node*3+0]; pd1 = pos[node*3+1]; pd2 = pos[node*3+2];
            }
        }
        const int tn = min(targ + STRIDE, NTILES - 1);
        srcN = srcArr[tn*64 + e];
    };
    issue(blockIdx.x);   // tile0's gather in flight under the weight build

    // ---- per-wave weight fragments: 2 m-tiles (GEMM1), 2 ch-frags (GEMM2) ----
    short8 wah[2][NS1];
    float  bav[2][4];
    #pragma unroll
    for (int mt = 0; mt < 2; ++mt) {
        const int h = hb*32 + mt*16 + c;
        #pragma unroll
        for (int pk = 0; pk < NS1; ++pk) {
            short8 fh;
            #pragma unroll
            for (int j = 0; j < 8; ++j) {
                const int k = pk*32 + g*8 + j;
                fh[j] = (k < K1) ? f2bf(wa[k*H + h]) : (short)0;
            }
            wah[mt][pk] = fh;
        }
        #pragma unroll
        for (int r = 0; r < 4; ++r) bav[mt][r] = ba[hb*32 + mt*16 + g*4 + r];
    }
    short8 wbh[2][NS2];
    float  bbsc[2];
    #pragma unroll
    for (int cb = 0; cb < 2; ++cb) {
        const int o = cb2*32 + cb*16 + c;
        #pragma unroll
        for (int pk = 0; pk < NS2; ++pk) {
            short8 fh;
            #pragma unroll
            for (int j = 0; j < 8; ++j) {
                const int k = pk*32 + g*8 + j;   // k < H always
                fh[j] = f2bf(wb[k*O + o]);
            }
            wbh[cb][pk] = fh;
        }
        bbsc[cb] = bb[o];
    }
    __syncthreads();

    for (int tile = blockIdx.x; tile < NTILES; tile += STRIDE) {
        // ---- stage x(tile) from prefetched regs ----
        if constexpr (CIN == 3) {
            if (rep == 0) {
                short8 hv;
                hv[0] = f2bf(ps0); hv[1] = f2bf(ps1); hv[2] = f2bf(ps2);
                hv[3] = f2bf(ps0 - pd0);
                hv[4] = f2bf(ps1 - pd1);
                hv[5] = f2bf(ps2 - pd2);
                hv[6] = 0; hv[7] = 0;
                *(short8*)(xs + e*RSX) = hv;
            }
        } else {
            *(short8*)(xs + e*RSX + rep*8) = pA;   // exact row coverage
            if (rep == 0) {
                short8 hv;
                hv[0] = f2bf(ps0 - pd0);
                hv[1] = f2bf(ps1 - pd1);
                hv[2] = f2bf(ps2 - pd2);
                hv[3]=0; hv[4]=0; hv[5]=0; hv[6]=0; hv[7]=0;
                *(short8*)(xs + e*RSX + CIN) = hv;
            }
        }
        barrier_lds_only();

        // ---- issue next tile's gather; lands under GEMM1+GEMM2 ----
        issue(min(tile + STRIDE, NTILES - 1));

        // ---- GEMM1: C1[h][edge] = wa^T x + ba (this wave: hb, eg1) ----
        {
            float4v C1[2][NT1];
            #pragma unroll
            for (int mt = 0; mt < 2; ++mt)
                #pragma unroll
                for (int nt = 0; nt < NT1; ++nt)
                    #pragma unroll
                    for (int r = 0; r < 4; ++r) C1[mt][nt][r] = bav[mt][r];
            #pragma unroll
            for (int pk = 0; pk < NS1; ++pk)
                #pragma unroll
                for (int nt = 0; nt < NT1; ++nt) {
                    short8 xh = *(const short8*)(xs + (eg1*E1 + nt*16 + c)*RSX + pk*32 + g*8);
                    #pragma unroll
                    for (int mt = 0; mt < 2; ++mt)   // one read feeds 2 MFMAs
                        C1[mt][nt] = __builtin_amdgcn_mfma_f32_16x16x32_bf16(wah[mt][pk], xh, C1[mt][nt], 0,0,0);
                }
            // epilogue1: relu -> packed bf16 -> ys[edge][h]
            #pragma unroll
            for (int mt = 0; mt < 2; ++mt)
                #pragma unroll
                for (int nt = 0; nt < NT1; ++nt) {
                    uint2v pv;
                    pv[0] = cvt_pk_bf16(fmaxf(C1[mt][nt][0], 0.f), fmaxf(C1[mt][nt][1], 0.f));
                    pv[1] = cvt_pk_bf16(fmaxf(C1[mt][nt][2], 0.f), fmaxf(C1[mt][nt][3], 0.f));
                    *(uint2v*)(ys + (eg1*E1 + nt*16 + c)*RSY + hb*32 + mt*16 + g*4) = pv;
                }
        }
        barrier_lds_only();

        // ---- GEMM2 (flipped): C2[edge][o] = y wb + bb (this wave: cb2, eg2) ----
        float4v C2[MT2][2];
        #pragma unroll
        for (int mt = 0; mt < MT2; ++mt)
            #pragma unroll
            for (int cb = 0; cb < 2; ++cb)
                #pragma unroll
                for (int r = 0; r < 4; ++r) C2[mt][cb][r] = bbsc[cb];
        #pragma unroll
        for (int pk = 0; pk < NS2; ++pk)
            #pragma unroll
            for (int mt = 0; mt < MT2; ++mt) {
                short8 yh = *(const short8*)(ys + (eg2*E2 + mt*16 + c)*RSY + pk*32 + g*8);
                #pragma unroll
                for (int cb = 0; cb < 2; ++cb)       // one read feeds 2 MFMAs
                    C2[mt][cb] = __builtin_amdgcn_mfma_f32_16x16x32_bf16(yh, wbh[cb][pk], C2[mt][cb], 0,0,0);
            }
        // epilogue2: rows are edges -> lane-local max over r, then VALU
        // permlane reduce over g; lanes 0..15 store 16 consecutive channels.
        #pragma unroll
        for (int mt = 0; mt < MT2; ++mt)
            #pragma unroll
            for (int cb = 0; cb < 2; ++cb) {
                float m = fmaxf(fmaxf(C2[mt][cb][0], C2[mt][cb][1]),
                                fmaxf(C2[mt][cb][2], C2[mt][cb][3]));
                m = red_groups_max(m);
                if (lane < 16) {
                    const int node = tile*4 + eg2*(E2/16) + mt;
                    hout[(size_t)node*O + cb2*32 + cb*16 + lane] = (ushort_t)f2bf(fmaxf(m, 0.f));
                }
            }
        // 2 barriers/tile is safe: a wave reaches stage(t+1) only after epi2(t);
        // barrier-1(t+1) orders xs writes vs all waves' GEMM1(t) reads, and
        // between barriers GEMM2 touches only ys.
    }
}

__global__ void zero_k(float* __restrict__ p, int n)
{
    const int i = blockIdx.x * 256 + threadIdx.x;
    if (i < n) p[i] = 0.f;
}

// batch is SORTED: register accumulation, one atomic per batch-change.
__global__ void pool_k(const ushort_t* __restrict__ h3, const int* __restrict__ batch,
                       float* __restrict__ pooled, float* __restrict__ counts)
{
    const int c    = threadIdx.x & 127;
    const int half = threadIdx.x >> 7;
    const int nbeg = blockIdx.x * 128 + half * 64;
    if (nbeg >= NNODES) return;
    const int nend = min(nbeg + 64, NNODES);

    int   cur = batch[nbeg];
    float acc = 0.f;
    int   runlen = 0;
    for (int n = nbeg; n < nend; ++n) {
        const int b = batch[n];
        if (b != cur) {
            atomicAdd(pooled + cur*128 + c, acc);
            if (c == 0) atomicAdd(counts + cur, (float)runlen);
            acc = 0.f; runlen = 0; cur = b;
        }
        acc += b2f((short)h3[(size_t)n * 128 + c]);
        ++runlen;
    }
    atomicAdd(pooled + cur*128 + c, acc);
    if (c == 0) atomicAdd(counts + cur, (float)runlen);
}

__global__ void reg_k(const float* __restrict__ pooled, const float* __restrict__ counts,
                      const float* __restrict__ wr1, const float* __restrict__ br1,
                      const float* __restrict__ wr2, const float* __restrict__ br2,
                      float* __restrict__ out)
{
    const int b = blockIdx.x;     // 64 blocks
    const int h = threadIdx.x;    // 64 threads = hidden dim
    const float rc = 1.f / fmaxf(counts[b], 1.f);
    float acc = br1[h];
    #pragma unroll
    for (int k = 0; k < 128; ++k)
        acc = fmaf(pooled[b*128 + k] * rc, wr1[k*64 + h], acc);
    float v = acc * wr2[h];
    #pragma unroll
    for (int s = 1; s < 64; s <<= 1)
        v += __shfl_xor(v, s);
    if (h == 0) out[b] = 1.f / (1.f + expf(-(v + br2[0])));
}

extern "C" void kernel_launch(void* const* d_in, const int* in_sizes, int n_in,
                              void* d_out, int out_size, void* d_ws, size_t ws_size,
                              hipStream_t stream)
{
    const float* pos   = (const float*)d_in[0];
    const int*   eidx  = (const int*)d_in[1];    // [2,E]; row 0 = src
    const int*   batch = (const int*)d_in[2];
    // d_in[3] = timestep: unused by the reference
    const float *w1a = (const float*)d_in[4],  *b1a = (const float*)d_in[5];
    const float *w1b = (const float*)d_in[6],  *b1b = (const float*)d_in[7];
    const float *w2a = (const float*)d_in[8],  *b2a = (const float*)d_in[9];
    const float *w2b = (const float*)d_in[10], *b2b = (const float*)d_in[11];
    const float *w3a = (const float*)d_in[12], *b3a = (const float*)d_in[13];
    const float *w3b = (const float*)d_in[14], *b3b = (const float*)d_in[15];
    const float *wr1 = (const float*)d_in[16], *br1 = (const float*)d_in[17];
    const float *wr2 = (const float*)d_in[18], *br2 = (const float*)d_in[19];
    const int* srcArr = eidx;                    // row 0

    // bf16 hidden planes in workspace
    ushort_t* h1 = (ushort_t*)d_ws;                          // N*64 bf16
    ushort_t* h2 = h1 + (size_t)NNODES * 64;                 // N*64 bf16
    ushort_t* h3 = h2 + (size_t)NNODES * 64;                 // N*128 bf16
    float* pooled = (float*)(h3 + (size_t)NNODES * 128);     // B*128 f32
    float* counts = pooled + NBATCH * 128;                   // B
    float* out    = (float*)d_out;

    // Occupancy push (round-9 lesson: grid was the cap, not a pipe):
    // L1: 8 blocks/CU (64-reg cap via MINW=8, LDS 14.3KB x8 = 115KB).
    // L2/L3: 4 blocks/CU (VGPR=64 measured -> 8 waves/SIMD fills the reg file;
    // LDS 30.7KB x4 = 123KB). Grids sized to exact residency.
    layer_mfma<3,  64, 64, 4, 8><<<2048, dim3(256), 0, stream>>>(nullptr, pos, srcArr, w1a, b1a, w1b, b1b, h1);
    layer_mfma<64, 64, 64, 8, 4><<<1024, dim3(512), 0, stream>>>(h1,      pos, srcArr, w2a, b2a, w2b, b2b, h2);
    layer_mfma<64, 128,128,8, 4><<<1024, dim3(512), 0, stream>>>(h2,      pos, srcArr, w3a, b3a, w3b, b3b, h3);
    zero_k<<<(NBATCH*128 + NBATCH + 255)/256, dim3(256), 0, stream>>>(pooled, NBATCH*128 + NBATCH);
    pool_k<<<(NNODES + 127)/128, dim3(256), 0, stream>>>(h3, batch, pooled, counts);
    reg_k <<<NBATCH, dim3(64), 0, stream>>>(pooled, counts, wr1, br1, wr2, br2, out);
}

// Round 11
// 329.819 us; speedup vs baseline: 1.3391x; 1.3391x over previous
//
#include <hip/hip_runtime.h>
#include <math.h>

#define NNODES 100000
#define NEDGES 1600000
#define NBATCH 64
#define NTILES (NEDGES/64)   // 25000 tiles of 64 edges (4 nodes)

typedef __attribute__((ext_vector_type(8))) short  short8;
typedef __attribute__((ext_vector_type(4))) short  short4v;
typedef __attribute__((ext_vector_type(2))) unsigned int uint2v;
typedef __attribute__((ext_vector_type(4))) float  float4v;
typedef unsigned short ushort_t;

__device__ __forceinline__ short f2bf(float f) {           // RTNE fp32->bf16
    unsigned u = __builtin_bit_cast(unsigned, f);
    u += 0x7fffu + ((u >> 16) & 1u);
    return (short)(u >> 16);
}
__device__ __forceinline__ float b2f(short s) {
    unsigned u = ((unsigned)(unsigned short)s) << 16;
    return __builtin_bit_cast(float, u);
}
// 2×f32 -> packed 2×bf16 in one VALU op (lo -> low 16 bits).
__device__ __forceinline__ unsigned cvt_pk_bf16(float lo, float hi) {
    unsigned r;
    asm("v_cvt_pk_bf16_f32 %0, %1, %2" : "=v"(r) : "v"(lo), "v"(hi));
    return r;
}
// max over the 4 16-lane groups {c, c+16, c+32, c+48} without DS ops.
__device__ __forceinline__ float red_groups_max(float m) {
    unsigned a = __builtin_bit_cast(unsigned, m), b = a;
    asm("v_permlane16_swap_b32 %0, %1" : "+v"(a), "+v"(b));
    m = fmaxf(__builtin_bit_cast(float, a), __builtin_bit_cast(float, b));
    a = __builtin_bit_cast(unsigned, m); b = a;
    asm("v_permlane32_swap_b32 %0, %1" : "+v"(a), "+v"(b));
    return fmaxf(__builtin_bit_cast(float, a), __builtin_bit_cast(float, b));
}

// Barrier that releases LDS writes but leaves global prefetch loads in flight.
__device__ __forceinline__ void barrier_lds_only() {
    asm volatile("s_waitcnt lgkmcnt(0)" ::: "memory");
    __builtin_amdgcn_sched_barrier(0);
    __builtin_amdgcn_s_barrier();
    __builtin_amdgcn_sched_barrier(0);
}

// bf16 MFMA layer, two-stream software pipeline (round 11):
// occupancy is bracket-locked at 4 waves/SIMD (80-128 reg HW quantum, m69),
// so throughput must come from ILP. Double-buffered xs/ys; steady-state
// phase = { G2(t-1) || G1(t) || stage(t+1) || prefetch(t+2) } + ONE barrier.
// Every LDS buffer's writer/reader pair is separated by >=1 barrier:
//   G2 reads ys[q^1] (written by G1 last phase); G1 reads xs[q] (staged last
//   phase); stage writes xs[q^1] (read by G1 last phase); epi1 writes ys[q]
//   (read by G2 last phase).
// GEMM1: A = W^T (M=h), B = x^T (N=edges). GEMM2 flipped: A = y (M=edges),
// B = W (N=channels). D layout (m89): col=lane&15, row=(lane>>4)*4+reg.
template<int CIN, int H, int O, int NWAVES, int MINW>
__global__ __launch_bounds__(NWAVES*64, MINW)
void layer_mfma(const ushort_t* __restrict__ hin, const float* __restrict__ pos,
                const int* __restrict__ srcArr,
                const float* __restrict__ wa, const float* __restrict__ ba,
                const float* __restrict__ wb, const float* __restrict__ bb,
                ushort_t* __restrict__ hout)
{
    constexpr int K1   = CIN + 3;
    constexpr int S1   = ((K1 + 31) / 32) * 32;  // padded K of GEMM1
    constexpr int NS1  = S1 / 32;
    constexpr int NS2  = H / 32;
    // GEMM1 wave split: 32-wide h-block x edge-group
    constexpr int HB1  = H / 32;
    constexpr int EH1  = NWAVES / HB1;
    constexpr int E1   = 64 / EH1;               // edges per group
    constexpr int NT1  = E1 / 16;
    // GEMM2 wave split: 32-wide channel-block x edge-group
    constexpr int CB2  = O / 32;
    constexpr int EH2  = NWAVES / CB2;
    constexpr int E2   = 64 / EH2;
    constexpr int MT2  = E2 / 16;
    constexpr int RSX  = S1 + 8;                 // x row stride (shorts)
    constexpr int RSY  = H + 8;
    constexpr int XSZ  = 64 * RSX;
    constexpr int YSZ  = 64 * RSY;

    __shared__ short smem[2*(XSZ + YSZ)];        // xs0|xs1|ys0|ys1

    const int tid  = threadIdx.x;
    const int lane = tid & 63;
    const int w    = tid >> 6;   // wave id
    const int g    = lane >> 4;  // k-group / row-group
    const int c    = lane & 15;
    const int e    = tid & 63;   // edge-in-tile this thread stages
    const int rep  = tid >> 6;   // 8-short slice of the row this thread stages
    const int hb   = w / EH1;    // GEMM1 h-block (32 wide)
    const int eg1  = w % EH1;    // GEMM1 edge group
    const int cb2  = w / EH2;    // GEMM2 channel block (32 wide)
    const int eg2  = w % EH2;    // GEMM2 edge group
    const int STRIDE = gridDim.x;

    // Zero both buffer sets once: K-pad columns must read as 0.
    {
        short4v z4 = (short4v)0;
        for (int i = tid; i < (2*(XSZ + YSZ))/4; i += NWAVES*64)
            ((short4v*)smem)[i] = z4;
    }

    // ---- prefetch state: gather rows/pos for tile `targ`, then advance srcN.
    int srcN = srcArr[blockIdx.x * 64 + e];
    short8 pA;
    float ps0, ps1, ps2, pd0, pd1, pd2;
    auto issue = [&](int targ) {
        const int src = srcN;
        if constexpr (CIN == 3) {
            if (rep == 0) {
                ps0 = pos[src*3+0]; ps1 = pos[src*3+1]; ps2 = pos[src*3+2];
                const int node = targ*4 + (e >> 4);
                pd0 = pos[node*3+0]; pd1 = pos[node*3+1]; pd2 = pos[node*3+2];
            }
        } else {
            pA = *(const short8*)(hin + (size_t)src * CIN + rep*8);
            if (rep == 0) {
                ps0 = pos[src*3+0]; ps1 = pos[src*3+1]; ps2 = pos[src*3+2];
                const int node = targ*4 + (e >> 4);
                pd0 = pos[node*3+0]; pd1 = pos[node*3+1]; pd2 = pos[node*3+2];
            }
        }
        const int tn = min(targ + STRIDE, NTILES - 1);
        srcN = srcArr[tn*64 + e];
    };
    issue(blockIdx.x);   // tile0's gather in flight under the weight build

    // ---- per-wave weight fragments: 2 m-tiles (GEMM1), 2 ch-frags (GEMM2) ----
    short8 wah[2][NS1];
    float  bav[2][4];
    #pragma unroll
    for (int mt = 0; mt < 2; ++mt) {
        const int h = hb*32 + mt*16 + c;
        #pragma unroll
        for (int pk = 0; pk < NS1; ++pk) {
            short8 fh;
            #pragma unroll
            for (int j = 0; j < 8; ++j) {
                const int k = pk*32 + g*8 + j;
                fh[j] = (k < K1) ? f2bf(wa[k*H + h]) : (short)0;
            }
            wah[mt][pk] = fh;
        }
        #pragma unroll
        for (int r = 0; r < 4; ++r) bav[mt][r] = ba[hb*32 + mt*16 + g*4 + r];
    }
    short8 wbh[2][NS2];
    float  bbsc[2];
    #pragma unroll
    for (int cb = 0; cb < 2; ++cb) {
        const int o = cb2*32 + cb*16 + c;
        #pragma unroll
        for (int pk = 0; pk < NS2; ++pk) {
            short8 fh;
            #pragma unroll
            for (int j = 0; j < 8; ++j) {
                const int k = pk*32 + g*8 + j;   // k < H always
                fh[j] = f2bf(wb[k*O + o]);
            }
            wbh[cb][pk] = fh;
        }
        bbsc[cb] = bb[o];
    }
    __syncthreads();

    // ---- phase building blocks ----
    auto stage = [&](short* xsd) {               // write prefetched x-rows
        if constexpr (CIN == 3) {
            if (rep == 0) {
                short8 hv;
                hv[0] = f2bf(ps0); hv[1] = f2bf(ps1); hv[2] = f2bf(ps2);
                hv[3] = f2bf(ps0 - pd0);
                hv[4] = f2bf(ps1 - pd1);
                hv[5] = f2bf(ps2 - pd2);
                hv[6] = 0; hv[7] = 0;
                *(short8*)(xsd + e*RSX) = hv;
            }
        } else {
            *(short8*)(xsd + e*RSX + rep*8) = pA;   // exact row coverage
            if (rep == 0) {
                short8 hv;
                hv[0] = f2bf(ps0 - pd0);
                hv[1] = f2bf(ps1 - pd1);
                hv[2] = f2bf(ps2 - pd2);
                hv[3]=0; hv[4]=0; hv[5]=0; hv[6]=0; hv[7]=0;
                *(short8*)(xsd + e*RSX + CIN) = hv;
            }
        }
    };

    auto g1 = [&](const short* xsr, short* ysw) {   // GEMM1 + epi1
        float4v C1[2][NT1];
        #pragma unroll
        for (int mt = 0; mt < 2; ++mt)
            #pragma unroll
            for (int nt = 0; nt < NT1; ++nt)
                #pragma unroll
                for (int r = 0; r < 4; ++r) C1[mt][nt][r] = bav[mt][r];
        #pragma unroll
        for (int pk = 0; pk < NS1; ++pk)
            #pragma unroll
            for (int nt = 0; nt < NT1; ++nt) {
                short8 xh = *(const short8*)(xsr + (eg1*E1 + nt*16 + c)*RSX + pk*32 + g*8);
                #pragma unroll
                for (int mt = 0; mt < 2; ++mt)   // one read feeds 2 MFMAs
                    C1[mt][nt] = __builtin_amdgcn_mfma_f32_16x16x32_bf16(wah[mt][pk], xh, C1[mt][nt], 0,0,0);
            }
        #pragma unroll
        for (int mt = 0; mt < 2; ++mt)
            #pragma unroll
            for (int nt = 0; nt < NT1; ++nt) {
                uint2v pv;
                pv[0] = cvt_pk_bf16(fmaxf(C1[mt][nt][0], 0.f), fmaxf(C1[mt][nt][1], 0.f));
                pv[1] = cvt_pk_bf16(fmaxf(C1[mt][nt][2], 0.f), fmaxf(C1[mt][nt][3], 0.f));
                *(uint2v*)(ysw + (eg1*E1 + nt*16 + c)*RSY + hb*32 + mt*16 + g*4) = pv;
            }
    };

    auto g2 = [&](const short* ysr, int outTile) {  // GEMM2 + epi2 store
        float4v C2[MT2][2];
        #pragma unroll
        for (int mt = 0; mt < MT2; ++mt)
            #pragma unroll
            for (int cb = 0; cb < 2; ++cb)
                #pragma unroll
                for (int r = 0; r < 4; ++r) C2[mt][cb][r] = bbsc[cb];
        #pragma unroll
        for (int pk = 0; pk < NS2; ++pk)
            #pragma unroll
            for (int mt = 0; mt < MT2; ++mt) {
                short8 yh = *(const short8*)(ysr + (eg2*E2 + mt*16 + c)*RSY + pk*32 + g*8);
                #pragma unroll
                for (int cb = 0; cb < 2; ++cb)   // one read feeds 2 MFMAs
                    C2[mt][cb] = __builtin_amdgcn_mfma_f32_16x16x32_bf16(yh, wbh[cb][pk], C2[mt][cb], 0,0,0);
            }
        #pragma unroll
        for (int mt = 0; mt < MT2; ++mt)
            #pragma unroll
            for (int cb = 0; cb < 2; ++cb) {
                float m = fmaxf(fmaxf(C2[mt][cb][0], C2[mt][cb][1]),
                                fmaxf(C2[mt][cb][2], C2[mt][cb][3]));
                m = red_groups_max(m);
                if (lane < 16) {
                    const int node = outTile*4 + eg2*(E2/16) + mt;
                    hout[(size_t)node*O + cb2*32 + cb*16 + lane] = (ushort_t)f2bf(fmaxf(m, 0.f));
                }
            }
    };

    // ---- prologue: stage tile0 into xs[0]; prefetch tile1 ----
    stage(smem);                                     // xs parity 0
    issue(min(blockIdx.x + STRIDE, NTILES - 1));     // pA <- tile1 rows
    barrier_lds_only();

    // ---- pipelined main loop: ONE barrier per tile ----
    int i = 0;
    int prevTile = -1;
    for (int tile = blockIdx.x; tile < NTILES; tile += STRIDE, ++i) {
        const int q = i & 1;
        short* xs_cur = smem + q*XSZ;
        short* xs_nxt = smem + (q^1)*XSZ;
        short* ys_cur = smem + 2*XSZ + q*YSZ;
        short* ys_prv = smem + 2*XSZ + (q^1)*YSZ;

        if (prevTile >= 0) g2(ys_prv, prevTile);     // finish previous tile
        g1(xs_cur, ys_cur);                          // current tile -> ys
        stage(xs_nxt);                               // next tile's x (prefetched)
        issue(min(tile + 2*STRIDE, NTILES - 1));     // prefetch tile+2
        barrier_lds_only();
        prevTile = tile;
    }
    // ---- drain: GEMM2 of the last tile ----
    if (prevTile >= 0) {
        const int qf = (i - 1) & 1;
        g2(smem + 2*XSZ + qf*YSZ, prevTile);
    }
}

__global__ void zero_k(float* __restrict__ p, int n)
{
    const int i = blockIdx.x * 256 + threadIdx.x;
    if (i < n) p[i] = 0.f;
}

// batch is SORTED: register accumulation, one atomic per batch-change.
__global__ void pool_k(const ushort_t* __restrict__ h3, const int* __restrict__ batch,
                       float* __restrict__ pooled, float* __restrict__ counts)
{
    const int c    = threadIdx.x & 127;
    const int half = threadIdx.x >> 7;
    const int nbeg = blockIdx.x * 128 + half * 64;
    if (nbeg >= NNODES) return;
    const int nend = min(nbeg + 64, NNODES);

    int   cur = batch[nbeg];
    float acc = 0.f;
    int   runlen = 0;
    for (int n = nbeg; n < nend; ++n) {
        const int b = batch[n];
        if (b != cur) {
            atomicAdd(pooled + cur*128 + c, acc);
            if (c == 0) atomicAdd(counts + cur, (float)runlen);
            acc = 0.f; runlen = 0; cur = b;
        }
        acc += b2f((short)h3[(size_t)n * 128 + c]);
        ++runlen;
    }
    atomicAdd(pooled + cur*128 + c, acc);
    if (c == 0) atomicAdd(counts + cur, (float)runlen);
}

__global__ void reg_k(const float* __restrict__ pooled, const float* __restrict__ counts,
                      const float* __restrict__ wr1, const float* __restrict__ br1,
                      const float* __restrict__ wr2, const float* __restrict__ br2,
                      float* __restrict__ out)
{
    const int b = blockIdx.x;     // 64 blocks
    const int h = threadIdx.x;    // 64 threads = hidden dim
    const float rc = 1.f / fmaxf(counts[b], 1.f);
    float acc = br1[h];
    #pragma unroll
    for (int k = 0; k < 128; ++k)
        acc = fmaf(pooled[b*128 + k] * rc, wr1[k*64 + h], acc);
    float v = acc * wr2[h];
    #pragma unroll
    for (int s = 1; s < 64; s <<= 1)
        v += __shfl_xor(v, s);
    if (h == 0) out[b] = 1.f / (1.f + expf(-(v + br2[0])));
}

extern "C" void kernel_launch(void* const* d_in, const int* in_sizes, int n_in,
                              void* d_out, int out_size, void* d_ws, size_t ws_size,
                              hipStream_t stream)
{
    const float* pos   = (const float*)d_in[0];
    const int*   eidx  = (const int*)d_in[1];    // [2,E]; row 0 = src
    const int*   batch = (const int*)d_in[2];
    // d_in[3] = timestep: unused by the reference
    const float *w1a = (const float*)d_in[4],  *b1a = (const float*)d_in[5];
    const float *w1b = (const float*)d_in[6],  *b1b = (const float*)d_in[7];
    const float *w2a = (const float*)d_in[8],  *b2a = (const float*)d_in[9];
    const float *w2b = (const float*)d_in[10], *b2b = (const float*)d_in[11];
    const float *w3a = (const float*)d_in[12], *b3a = (const float*)d_in[13];
    const float *w3b = (const float*)d_in[14], *b3b = (const float*)d_in[15];
    const float *wr1 = (const float*)d_in[16], *br1 = (const float*)d_in[17];
    const float *wr2 = (const float*)d_in[18], *br2 = (const float*)d_in[19];
    const int* srcArr = eidx;                    // row 0

    // bf16 hidden planes in workspace
    ushort_t* h1 = (ushort_t*)d_ws;                          // N*64 bf16
    ushort_t* h2 = h1 + (size_t)NNODES * 64;                 // N*64 bf16
    ushort_t* h3 = h2 + (size_t)NNODES * 64;                 // N*128 bf16
    float* pooled = (float*)(h3 + (size_t)NNODES * 128);     // B*128 f32
    float* counts = pooled + NBATCH * 128;                   // B
    float* out    = (float*)d_out;

    // MINW=4 everywhere (128-reg budget; round-10 lesson: tighter caps spill).
    // Occupancy is bracket-locked at 16 waves/CU; grids at exact residency:
    // L1 4 blocks/CU x 4 waves, L2/L3 2 blocks/CU x 8 waves.
    layer_mfma<3,  64, 64, 4, 4><<<1024, dim3(256), 0, stream>>>(nullptr, pos, srcArr, w1a, b1a, w1b, b1b, h1);
    layer_mfma<64, 64, 64, 8, 4><<< 512, dim3(512), 0, stream>>>(h1,      pos, srcArr, w2a, b2a, w2b, b2b, h2);
    layer_mfma<64, 128,128,8, 4><<< 512, dim3(512), 0, stream>>>(h2,      pos, srcArr, w3a, b3a, w3b, b3b, h3);
    zero_k<<<(NBATCH*128 + NBATCH + 255)/256, dim3(256), 0, stream>>>(pooled, NBATCH*128 + NBATCH);
    pool_k<<<(NNODES + 127)/128, dim3(256), 0, stream>>>(h3, batch, pooled, counts);
    reg_k <<<NBATCH, dim3(64), 0, stream>>>(pooled, counts, wr1, br1, wr2, br2, out);
}